// Round 10
// baseline (49.098 us; speedup 1.0000x reference)
//
#include <hip/hip_runtime.h>

typedef unsigned short ushort_t;
typedef __bf16 bf16x8 __attribute__((ext_vector_type(8)));
typedef float f32x4 __attribute__((ext_vector_type(4)));

#define AS1 __attribute__((address_space(1)))
#define AS3 __attribute__((address_space(3)))

__device__ __forceinline__ ushort_t f2bf(float f) {
    unsigned u = __builtin_bit_cast(unsigned, f);
    u = (u + 0x7fffu + ((u >> 16) & 1u)) >> 16;
    return (ushort_t)u;
}

__device__ __forceinline__ void async16(void* lds, const void* g) {
    __builtin_amdgcn_global_load_lds((const AS1 unsigned int*)g,
                                     (AS3 unsigned int*)lds, 16, 0, 0);
}

__device__ __forceinline__ void softmax2(const float* __restrict__ sig, float& s0, float& s1) {
    float a = sig[0], b = sig[1];
    float m = fmaxf(a, b);
    float e0 = __expf(a - m), e1 = __expf(b - m);
    float inv = 1.0f / (e0 + e1);
    s0 = e0 * inv; s1 = e1 * inv;
}

// toeplitz value: W_toep[k][o]
__device__ __forceinline__ float toep_val(const float* __restrict__ Wseed, int k, int o) {
    return (k >= o) ? Wseed[(size_t)(k - o) << 10] : Wseed[o - k];
}

// ---------------- prep: W_core^T bf16 (x consumed fp32 by GEMM) ----------------
// 256 blocks, each a 64x64 (k,o) tile: read Wseed rows coalesced, transpose via LDS,
// write Wt[o][k] bf16 coalesced.
__global__ __launch_bounds__(256) void prep_w_kernel(const float* __restrict__ Wseed,
                                                     const float* __restrict__ Wsig,
                                                     ushort_t* __restrict__ Wt) {
    __shared__ float T[64][65];
    int bb = blockIdx.x;                        // 0..255
    int k0 = (bb >> 4) * 64;
    int o0 = (bb & 15) * 64;
    int t = threadIdx.x;
    #pragma unroll
    for (int i = 0; i < 4; ++i) {
        int lin = t + i * 256;
        int kr = lin >> 4;
        int c4 = lin & 15;
        float4 v = *(const float4*)&Wseed[(size_t)(k0 + kr) * 1024 + o0 + c4 * 4];
        T[kr][c4 * 4 + 0] = v.x;
        T[kr][c4 * 4 + 1] = v.y;
        T[kr][c4 * 4 + 2] = v.z;
        T[kr][c4 * 4 + 3] = v.w;
    }
    __syncthreads();
    float s0, s1; softmax2(Wsig, s0, s1);
    #pragma unroll
    for (int i = 0; i < 2; ++i) {
        int lin = t + i * 256;
        int oo = lin >> 3;
        int kq = (lin & 7) * 8;
        unsigned r[4];
        #pragma unroll
        for (int q = 0; q < 4; ++q) {
            float v0 = s0 * T[kq + 2 * q + 0][oo] + s1 * toep_val(Wseed, k0 + kq + 2 * q + 0, o0 + oo);
            float v1 = s0 * T[kq + 2 * q + 1][oo] + s1 * toep_val(Wseed, k0 + kq + 2 * q + 1, o0 + oo);
            r[q] = (unsigned)f2bf(v0) | ((unsigned)f2bf(v1) << 16);
        }
        *(uint4*)&Wt[(size_t)(o0 + oo) * 1024 + k0 + kq] = make_uint4(r[0], r[1], r[2], r[3]);
    }
}

// ---------------- main GEMM: R4 structure + fused fp32-A staging ----------------
// 128x128 tile, BK=32, grid 512 = 2 blocks/CU (external TLP hides barrier stalls).
// A: fp32 x -> regs (issued BEFORE compute) -> cvt bf16 -> ds_write AFTER compute.
// B: async16 from prepped Wt (verified linear layout). Double-buffered LDS, one
// vmcnt(0)+lgkmcnt(0)+barrier per K-step.
#define BM 128
#define BN 128
#define BK 32
#define NKT 32   // 1024 / 32

__global__ __launch_bounds__(256, 2) void gemm_kernel(const float* __restrict__ Xf,
                                                      const ushort_t* __restrict__ Wt,
                                                      const float* __restrict__ bseed,
                                                      const float* __restrict__ bsig,
                                                      const float* __restrict__ asig,
                                                      float* __restrict__ out) {
    // double buffer: [buf][A(4096) | B(4096)] ushorts = 32 KB total
    __shared__ ushort_t lds[16384];
    ushort_t* At0 = lds;
    ushort_t* Bt0 = lds + 4096;
    ushort_t* At1 = lds + 8192;
    ushort_t* Bt1 = lds + 12288;

    const int t = threadIdx.x;        // 0..255
    const int wv = t >> 6;
    const int lane = t & 63;

    // XCD-aware swizzle (512 blocks, 512%8==0 -> bijective)
    const int orig = blockIdx.x;
    const int g = orig & 7;
    const int within = orig >> 3;           // 0..63
    const int rb = g * 8 + (within >> 3);   // row-block 0..63 (8 per XCD)
    const int cb = within & 7;              // col-block 0..7
    const int brow = rb * BM;
    const int bcol = cb * BN;

    // staging: thread t covers 8 contiguous elems; 4 threads per 32-elem row
    const int r0 = t >> 2;            // 0..63
    const int kc = (t & 3) * 8;       // 0,8,16,24
    const float*    gX0 = Xf + (size_t)(brow + r0) * 1024 + kc;       // fp32 rows 0..63
    const float*    gX1 = Xf + (size_t)(brow + 64 + r0) * 1024 + kc;  // rows 64..127
    const ushort_t* gB0 = Wt + (size_t)(bcol + r0) * 1024 + kc;
    const ushort_t* gB1 = Wt + (size_t)(bcol + 64 + r0) * 1024 + kc;

    f32x4 acc[4][4];
    #pragma unroll
    for (int i = 0; i < 4; ++i)
        #pragma unroll
        for (int j = 0; j < 4; ++j) acc[i][j] = (f32x4){0.f, 0.f, 0.f, 0.f};

    const int wr = (wv >> 1) * 64;
    const int wcn = (wv & 1) * 64;
    const int fr = lane & 15;
    const int kg = (lane >> 4) * 8;

    // epilogue scalars precomputed + pinned (keeps their loads out of the loop)
    float bs0, bs1, as0, as1;
    softmax2(bsig, bs0, bs1);
    softmax2(asig, as0, as1);
    float bias[4];
    #pragma unroll
    for (int ni = 0; ni < 4; ++ni)
        bias[ni] = bs0 * bseed[bcol + wcn + ni * 16 + fr];
    asm volatile("" :: "v"(bias[0]), "v"(bias[1]), "v"(bias[2]), "v"(bias[3]),
                       "v"(as0), "v"(as1));
    asm volatile("" ::: "memory");

    // wave-uniform LDS staging bases for B (lane*16B implicit in global_load_lds)
    const int sA = wv * 512;
    const int sA2 = 2048 + wv * 512;
    // A staging regs (statically indexed)
    f32x4 ar0, ar1, ar2, ar3;

#define LOADA(ko)                                          \
    do {                                                   \
        ar0 = *(const f32x4*)(gX0 + (ko));                 \
        ar1 = *(const f32x4*)(gX0 + (ko) + 4);             \
        ar2 = *(const f32x4*)(gX1 + (ko));                 \
        ar3 = *(const f32x4*)(gX1 + (ko) + 4);             \
    } while (0)

// thread t's 16B lands at linear ushort offset t*8 (== r0*32 + kc): identical to
// the async16 layout verified in R1-R4.
#define WRITEA(Abuf)                                       \
    do {                                                   \
        bf16x8 v0, v1;                                     \
        _Pragma("unroll")                                  \
        for (int j = 0; j < 4; ++j) {                      \
            v0[j]     = (__bf16)ar0[j];                    \
            v0[4 + j] = (__bf16)ar1[j];                    \
            v1[j]     = (__bf16)ar2[j];                    \
            v1[4 + j] = (__bf16)ar3[j];                    \
        }                                                  \
        *(bf16x8*)&(Abuf)[t * 8] = v0;                     \
        *(bf16x8*)&(Abuf)[2048 + t * 8] = v1;              \
    } while (0)

#define STAGEB(Bbuf, ko)                                   \
    do {                                                   \
        async16((Bbuf) + sA,  gB0 + (ko));                 \
        async16((Bbuf) + sA2, gB1 + (ko));                 \
    } while (0)

#define COMPUTE(Abuf, Bbuf)                                                        \
    do {                                                                           \
        bf16x8 af[4], bf[4];                                                       \
        _Pragma("unroll")                                                          \
        for (int mi = 0; mi < 4; ++mi)                                             \
            af[mi] = *(const bf16x8*)&(Abuf)[(wr + mi * 16 + fr) * BK + kg];       \
        _Pragma("unroll")                                                          \
        for (int ni = 0; ni < 4; ++ni)                                             \
            bf[ni] = *(const bf16x8*)&(Bbuf)[(wcn + ni * 16 + fr) * BK + kg];      \
        _Pragma("unroll")                                                          \
        for (int mi = 0; mi < 4; ++mi)                                             \
            _Pragma("unroll")                                                      \
            for (int ni = 0; ni < 4; ++ni)                                         \
                acc[mi][ni] = __builtin_amdgcn_mfma_f32_16x16x32_bf16(             \
                    af[mi], bf[ni], acc[mi][ni], 0, 0, 0);                         \
    } while (0)

#define SYNC() do { asm volatile("s_waitcnt vmcnt(0) lgkmcnt(0)" ::: "memory");    \
                    __builtin_amdgcn_s_barrier(); } while (0)

    // prologue: K-step 0 into buf0
    LOADA(0);
    STAGEB(Bt0, 0);
    WRITEA(At0);            // compiler inserts the vmcnt wait for ar* deps
    SYNC();
    // main: 15 double-iterations, static buffer names
    for (int it = 0; it < 15; ++it) {
        LOADA((2 * it + 1) * BK);             // A(t+1) issued early
        STAGEB(Bt1, (2 * it + 1) * BK);       // B(t+1) in flight across compute
        COMPUTE(At0, Bt0);                    // latency hides under MFMA
        WRITEA(At1);                          // cvt+ds_write after compute
        SYNC();
        LOADA((2 * it + 2) * BK);
        STAGEB(Bt0, (2 * it + 2) * BK);
        COMPUTE(At1, Bt1);
        WRITEA(At0);
        SYNC();
    }
    // tail: K-steps 30, 31
    LOADA(31 * BK);
    STAGEB(Bt1, 31 * BK);
    COMPUTE(At0, Bt0);
    WRITEA(At1);
    SYNC();
    COMPUTE(At1, Bt1);

    // epilogue: bias + activation mixture
    #pragma unroll
    for (int ni = 0; ni < 4; ++ni) {
        int col = bcol + wcn + ni * 16 + fr;
        #pragma unroll
        for (int mi = 0; mi < 4; ++mi) {
            int row = brow + wr + mi * 16 + (lane >> 4) * 4;
            #pragma unroll
            for (int r = 0; r < 4; ++r) {
                float v = acc[mi][ni][r] + bias[ni];
                out[(size_t)(row + r) * 1024 + col] = as0 * v + as1 * fmaxf(v, 0.f);
            }
        }
    }
#undef LOADA
#undef WRITEA
#undef STAGEB
#undef COMPUTE
#undef SYNC
}

// ---------------- fallback (only if workspace too small): naive fp32 ----------------
__global__ __launch_bounds__(256) void naive_kernel(const float* __restrict__ x,
                                                    const float* __restrict__ Wseed,
                                                    const float* __restrict__ bseed,
                                                    const float* __restrict__ Wsig,
                                                    const float* __restrict__ bsig,
                                                    const float* __restrict__ asig,
                                                    float* __restrict__ out) {
    int idx = blockIdx.x * 256 + threadIdx.x;
    int b = idx >> 10, o = idx & 1023;
    float ws0, ws1, bs0, bs1, as0, as1;
    softmax2(Wsig, ws0, ws1);
    softmax2(bsig, bs0, bs1);
    softmax2(asig, as0, as1);
    float s = 0.f;
    const float* xr = x + (size_t)b * 1024;
    for (int k = 0; k < 1024; ++k) {
        float wc = ws0 * Wseed[((size_t)k << 10) + o] + ws1 * toep_val(Wseed, k, o);
        s += xr[k] * wc;
    }
    float v = s + bs0 * bseed[o];
    out[idx] = as0 * v + as1 * fmaxf(v, 0.f);
}

extern "C" void kernel_launch(void* const* d_in, const int* in_sizes, int n_in,
                              void* d_out, int out_size, void* d_ws, size_t ws_size,
                              hipStream_t stream) {
    const float* x     = (const float*)d_in[0];
    const float* Wseed = (const float*)d_in[1];
    const float* bseed = (const float*)d_in[2];
    const float* Wsig  = (const float*)d_in[3];
    const float* bsig  = (const float*)d_in[4];
    const float* Asig  = (const float*)d_in[5];
    float* out = (float*)d_out;

    const size_t need = (2u << 20) + 1024;
    if (ws_size < need) {
        naive_kernel<<<dim3(8192 * 1024 / 256), dim3(256), 0, stream>>>(
            x, Wseed, bseed, Wsig, bsig, Asig, out);
        return;
    }

    ushort_t* Wt = (ushort_t*)d_ws;   // 2 MB: W_core^T bf16 [1024][1024]

    prep_w_kernel<<<dim3(256), dim3(256), 0, stream>>>(Wseed, Wsig, Wt);
    gemm_kernel<<<dim3(512), dim3(256), 0, stream>>>(x, Wt, bseed, bsig, Asig, out);
}

// Round 11
// 38.964 us; speedup vs baseline: 1.2601x; 1.2601x over previous
//
#include <hip/hip_runtime.h>

typedef unsigned short ushort_t;
typedef __bf16 bf16x8 __attribute__((ext_vector_type(8)));
typedef float f32x4 __attribute__((ext_vector_type(4)));

#define AS1 __attribute__((address_space(1)))
#define AS3 __attribute__((address_space(3)))

__device__ __forceinline__ ushort_t f2bf(float f) {
    unsigned u = __builtin_bit_cast(unsigned, f);
    u = (u + 0x7fffu + ((u >> 16) & 1u)) >> 16;
    return (ushort_t)u;
}

__device__ __forceinline__ void async16(void* lds, const void* g) {
    __builtin_amdgcn_global_load_lds((const AS1 unsigned int*)g,
                                     (AS3 unsigned int*)lds, 16, 0, 0);
}

__device__ __forceinline__ void softmax2(const float* __restrict__ sig, float& s0, float& s1) {
    float a = sig[0], b = sig[1];
    float m = fmaxf(a, b);
    float e0 = __expf(a - m), e1 = __expf(b - m);
    float inv = 1.0f / (e0 + e1);
    s0 = e0 * inv; s1 = e1 * inv;
}

// toeplitz value: W_toep[k][o]
__device__ __forceinline__ float toep_val(const float* __restrict__ Wseed, int k, int o) {
    return (k >= o) ? Wseed[(size_t)(k - o) << 10] : Wseed[o - k];
}

// ---------------- prep: W_core^T bf16 (x consumed fp32 by GEMM) ----------------
__global__ __launch_bounds__(256) void prep_w_kernel(const float* __restrict__ Wseed,
                                                     const float* __restrict__ Wsig,
                                                     ushort_t* __restrict__ Wt) {
    __shared__ float T[64][65];
    int bb = blockIdx.x;                        // 0..255
    int k0 = (bb >> 4) * 64;
    int o0 = (bb & 15) * 64;
    int t = threadIdx.x;
    #pragma unroll
    for (int i = 0; i < 4; ++i) {
        int lin = t + i * 256;
        int kr = lin >> 4;
        int c4 = lin & 15;
        float4 v = *(const float4*)&Wseed[(size_t)(k0 + kr) * 1024 + o0 + c4 * 4];
        T[kr][c4 * 4 + 0] = v.x;
        T[kr][c4 * 4 + 1] = v.y;
        T[kr][c4 * 4 + 2] = v.z;
        T[kr][c4 * 4 + 3] = v.w;
    }
    __syncthreads();
    float s0, s1; softmax2(Wsig, s0, s1);
    #pragma unroll
    for (int i = 0; i < 2; ++i) {
        int lin = t + i * 256;
        int oo = lin >> 3;
        int kq = (lin & 7) * 8;
        unsigned r[4];
        #pragma unroll
        for (int q = 0; q < 4; ++q) {
            float v0 = s0 * T[kq + 2 * q + 0][oo] + s1 * toep_val(Wseed, k0 + kq + 2 * q + 0, o0 + oo);
            float v1 = s0 * T[kq + 2 * q + 1][oo] + s1 * toep_val(Wseed, k0 + kq + 2 * q + 1, o0 + oo);
            r[q] = (unsigned)f2bf(v0) | ((unsigned)f2bf(v1) << 16);
        }
        *(uint4*)&Wt[(size_t)(o0 + oo) * 1024 + k0 + kq] = make_uint4(r[0], r[1], r[2], r[3]);
    }
}

// ---------------- main GEMM: R4 2-phase dbuf + fp32-A staged via async16 ----------
// 128x128 tile, BK=32, grid 512 = 2 blocks/CU.
// A: fp32 x staged DIRECTLY by global_load_lds (16KB/tile); bf16 cvt happens in
//    registers after the LDS read (VALU pipe, overlaps MFMA). No prep-x pass,
//    no reg-staging chain.
// A-path swizzle (rule #21, both-sides): linear LDS dest; global SOURCE 16B-chunk
//    pre-XOR'd with row&7; ds_read address XOR'd with row&7 -> 2-way banks (free).
// B: byte-identical to the R1-R4 verified async16 path (bf16 from Wt).
#define BM 128
#define BN 128
#define BK 32
#define NKT 32   // 1024 / 32

__global__ __launch_bounds__(256, 2) void gemm_kernel(const float* __restrict__ Xf,
                                                      const ushort_t* __restrict__ Wt,
                                                      const float* __restrict__ bseed,
                                                      const float* __restrict__ bsig,
                                                      const float* __restrict__ asig,
                                                      float* __restrict__ out) {
    // dbuf x (A 16KB fp32 + B 8KB bf16) = 48 KB
    __shared__ ushort_t lds[24576];
    ushort_t* At0 = lds;            // 8192 ushorts = 16KB (128 rows x 32 fp32)
    ushort_t* Bt0 = lds + 8192;     // 4096 ushorts = 8KB  (128 rows x 32 bf16)
    ushort_t* At1 = lds + 12288;
    ushort_t* Bt1 = lds + 20480;

    const int t = threadIdx.x;        // 0..255
    const int wv = t >> 6;
    const int lane = t & 63;

    // XCD-aware swizzle (512 blocks, bijective)
    const int orig = blockIdx.x;
    const int g = orig & 7;
    const int within = orig >> 3;           // 0..63
    const int rb = g * 8 + (within >> 3);   // row-block 0..63
    const int cb = within & 7;              // col-block 0..7
    const int brow = rb * BM;
    const int bcol = cb * BN;

    // ---- A staging map: 8 threads per 128B row; 16B chunk pre-swizzled ----
    const int arow_s = t >> 3;                       // 0..31 (call q adds q*32)
    const int achk  = (t & 7) ^ (arow_s & 7);        // inverse-swizzled chunk
    const float* gAsw = Xf + (size_t)(brow + arow_s) * 1024 + 4 * achk;

    // ---- B staging map (R1-R4 verified): 4 threads per 64B row ----
    const int r0b = t >> 2;            // 0..63
    const int kcb = (t & 3) * 8;       // 0,8,16,24
    const ushort_t* gB0 = Wt + (size_t)(bcol + r0b) * 1024 + kcb;
    const ushort_t* gB1 = Wt + (size_t)(bcol + 64 + r0b) * 1024 + kcb;

    f32x4 acc[4][4];
    #pragma unroll
    for (int i = 0; i < 4; ++i)
        #pragma unroll
        for (int j = 0; j < 4; ++j) acc[i][j] = (f32x4){0.f, 0.f, 0.f, 0.f};

    const int wr = (wv >> 1) * 64;
    const int wcn = (wv & 1) * 64;
    const int fr = lane & 15;
    const int kg = (lane >> 4) * 8;    // bf16 k-offset (B) / fp32 k-offset (A)
    const int c0 = (lane >> 4) * 2;    // A chunk base (16B units)

    // epilogue scalars precomputed (loads consumed before the loop)
    float bs0, bs1, as0, as1;
    softmax2(bsig, bs0, bs1);
    softmax2(asig, as0, as1);
    float bias[4];
    #pragma unroll
    for (int ni = 0; ni < 4; ++ni)
        bias[ni] = bs0 * bseed[bcol + wcn + ni * 16 + fr];
    asm volatile("" :: "v"(bias[0]), "v"(bias[1]), "v"(bias[2]), "v"(bias[3]),
                       "v"(as0), "v"(as1));
    asm volatile("" ::: "memory");

    // wave-uniform LDS staging bases
    const int sB = wv * 512;           // B: wave covers 1KB
    const int sB2 = 2048 + wv * 512;

// A: 4 async16 calls of 4KB (2048 ushorts) each; dest linear, source pre-swizzled
#define STAGEA(Abuf, ko)                                           \
    do {                                                           \
        async16((Abuf) + wv * 512,        gAsw + (ko));            \
        async16((Abuf) + 2048 + wv * 512, gAsw + 32768 + (ko));    \
        async16((Abuf) + 4096 + wv * 512, gAsw + 65536 + (ko));    \
        async16((Abuf) + 6144 + wv * 512, gAsw + 98304 + (ko));    \
    } while (0)

#define STAGEB(Bbuf, ko)                                   \
    do {                                                   \
        async16((Bbuf) + sB,  gB0 + (ko));                 \
        async16((Bbuf) + sB2, gB1 + (ko));                 \
    } while (0)

#define COMPUTE(Abuf, Bbuf)                                                        \
    do {                                                                           \
        const float* Af_ = (const float*)(Abuf);                                   \
        bf16x8 af[4], bf[4];                                                       \
        _Pragma("unroll")                                                          \
        for (int mi = 0; mi < 4; ++mi) {                                           \
            int row_ = wr + mi * 16 + fr;                                          \
            f32x4 lo_ = *(const f32x4*)&Af_[row_ * 32 + (((c0)     ^ (row_ & 7)) << 2)]; \
            f32x4 hi_ = *(const f32x4*)&Af_[row_ * 32 + (((c0 + 1) ^ (row_ & 7)) << 2)]; \
            bf16x8 a_;                                                             \
            _Pragma("unroll")                                                      \
            for (int j_ = 0; j_ < 4; ++j_) {                                       \
                a_[j_]     = (__bf16)lo_[j_];                                      \
                a_[4 + j_] = (__bf16)hi_[j_];                                      \
            }                                                                      \
            af[mi] = a_;                                                           \
        }                                                                          \
        _Pragma("unroll")                                                          \
        for (int ni = 0; ni < 4; ++ni)                                             \
            bf[ni] = *(const bf16x8*)&(Bbuf)[(wcn + ni * 16 + fr) * BK + kg];      \
        _Pragma("unroll")                                                          \
        for (int mi = 0; mi < 4; ++mi)                                             \
            _Pragma("unroll")                                                      \
            for (int ni = 0; ni < 4; ++ni)                                         \
                acc[mi][ni] = __builtin_amdgcn_mfma_f32_16x16x32_bf16(             \
                    af[mi], bf[ni], acc[mi][ni], 0, 0, 0);                         \
    } while (0)

#define SYNC() do { asm volatile("s_waitcnt vmcnt(0) lgkmcnt(0)" ::: "memory");    \
                    __builtin_amdgcn_s_barrier(); } while (0)

    // prologue: K-step 0 into buf0
    STAGEA(At0, 0);
    STAGEB(Bt0, 0);
    SYNC();
    // main: 15 double-iterations
    for (int it = 0; it < 15; ++it) {
        STAGEA(At1, (2 * it + 1) * BK);       // next tile in flight across compute
        STAGEB(Bt1, (2 * it + 1) * BK);
        COMPUTE(At0, Bt0);
        SYNC();
        STAGEA(At0, (2 * it + 2) * BK);
        STAGEB(Bt0, (2 * it + 2) * BK);
        COMPUTE(At1, Bt1);
        SYNC();
    }
    // tail: K-steps 30, 31
    STAGEA(At1, 31 * BK);
    STAGEB(Bt1, 31 * BK);
    COMPUTE(At0, Bt0);
    SYNC();
    COMPUTE(At1, Bt1);

    // epilogue: bias + activation mixture
    #pragma unroll
    for (int ni = 0; ni < 4; ++ni) {
        int col = bcol + wcn + ni * 16 + fr;
        #pragma unroll
        for (int mi = 0; mi < 4; ++mi) {
            int row = brow + wr + mi * 16 + (lane >> 4) * 4;
            #pragma unroll
            for (int r = 0; r < 4; ++r) {
                float v = acc[mi][ni][r] + bias[ni];
                out[(size_t)(row + r) * 1024 + col] = as0 * v + as1 * fmaxf(v, 0.f);
            }
        }
    }
#undef STAGEA
#undef STAGEB
#undef COMPUTE
#undef SYNC
}

// ---------------- fallback (only if workspace too small): naive fp32 ----------------
__global__ __launch_bounds__(256) void naive_kernel(const float* __restrict__ x,
                                                    const float* __restrict__ Wseed,
                                                    const float* __restrict__ bseed,
                                                    const float* __restrict__ Wsig,
                                                    const float* __restrict__ bsig,
                                                    const float* __restrict__ asig,
                                                    float* __restrict__ out) {
    int idx = blockIdx.x * 256 + threadIdx.x;
    int b = idx >> 10, o = idx & 1023;
    float ws0, ws1, bs0, bs1, as0, as1;
    softmax2(Wsig, ws0, ws1);
    softmax2(bsig, bs0, bs1);
    softmax2(asig, as0, as1);
    float s = 0.f;
    const float* xr = x + (size_t)b * 1024;
    for (int k = 0; k < 1024; ++k) {
        float wc = ws0 * Wseed[((size_t)k << 10) + o] + ws1 * toep_val(Wseed, k, o);
        s += xr[k] * wc;
    }
    float v = s + bs0 * bseed[o];
    out[idx] = as0 * v + as1 * fmaxf(v, 0.f);
}

extern "C" void kernel_launch(void* const* d_in, const int* in_sizes, int n_in,
                              void* d_out, int out_size, void* d_ws, size_t ws_size,
                              hipStream_t stream) {
    const float* x     = (const float*)d_in[0];
    const float* Wseed = (const float*)d_in[1];
    const float* bseed = (const float*)d_in[2];
    const float* Wsig  = (const float*)d_in[3];
    const float* bsig  = (const float*)d_in[4];
    const float* Asig  = (const float*)d_in[5];
    float* out = (float*)d_out;

    const size_t need = (2u << 20) + 1024;
    if (ws_size < need) {
        naive_kernel<<<dim3(8192 * 1024 / 256), dim3(256), 0, stream>>>(
            x, Wseed, bseed, Wsig, bsig, Asig, out);
        return;
    }

    ushort_t* Wt = (ushort_t*)d_ws;   // 2 MB: W_core^T bf16 [1024][1024]

    prep_w_kernel<<<dim3(256), dim3(256), 0, stream>>>(Wseed, Wsig, Wt);
    gemm_kernel<<<dim3(512), dim3(256), 0, stream>>>(x, Wt, bseed, bsig, Asig, out);
}

// Round 12
// 38.839 us; speedup vs baseline: 1.2642x; 1.0032x over previous
//
#include <hip/hip_runtime.h>

typedef unsigned short ushort_t;
typedef __bf16 bf16x8 __attribute__((ext_vector_type(8)));
typedef float f32x4 __attribute__((ext_vector_type(4)));

#define AS1 __attribute__((address_space(1)))
#define AS3 __attribute__((address_space(3)))

__device__ __forceinline__ ushort_t f2bf(float f) {
    unsigned u = __builtin_bit_cast(unsigned, f);
    u = (u + 0x7fffu + ((u >> 16) & 1u)) >> 16;
    return (ushort_t)u;
}

__device__ __forceinline__ void async16(void* lds, const void* g) {
    __builtin_amdgcn_global_load_lds((const AS1 unsigned int*)g,
                                     (AS3 unsigned int*)lds, 16, 0, 0);
}

__device__ __forceinline__ void softmax2(const float* __restrict__ sig, float& s0, float& s1) {
    float a = sig[0], b = sig[1];
    float m = fmaxf(a, b);
    float e0 = __expf(a - m), e1 = __expf(b - m);
    float inv = 1.0f / (e0 + e1);
    s0 = e0 * inv; s1 = e1 * inv;
}

// toeplitz value: W_toep[k][o]
__device__ __forceinline__ float toep_val(const float* __restrict__ Wseed, int k, int o) {
    return (k >= o) ? Wseed[(size_t)(k - o) << 10] : Wseed[o - k];
}

// ---------------- prep: W_core^T bf16 (x consumed fp32 by GEMM) ----------------
__global__ __launch_bounds__(256) void prep_w_kernel(const float* __restrict__ Wseed,
                                                     const float* __restrict__ Wsig,
                                                     ushort_t* __restrict__ Wt) {
    __shared__ float T[64][65];
    int bb = blockIdx.x;                        // 0..255
    int k0 = (bb >> 4) * 64;
    int o0 = (bb & 15) * 64;
    int t = threadIdx.x;
    #pragma unroll
    for (int i = 0; i < 4; ++i) {
        int lin = t + i * 256;
        int kr = lin >> 4;
        int c4 = lin & 15;
        float4 v = *(const float4*)&Wseed[(size_t)(k0 + kr) * 1024 + o0 + c4 * 4];
        T[kr][c4 * 4 + 0] = v.x;
        T[kr][c4 * 4 + 1] = v.y;
        T[kr][c4 * 4 + 2] = v.z;
        T[kr][c4 * 4 + 3] = v.w;
    }
    __syncthreads();
    float s0, s1; softmax2(Wsig, s0, s1);
    #pragma unroll
    for (int i = 0; i < 2; ++i) {
        int lin = t + i * 256;
        int oo = lin >> 3;
        int kq = (lin & 7) * 8;
        unsigned r[4];
        #pragma unroll
        for (int q = 0; q < 4; ++q) {
            float v0 = s0 * T[kq + 2 * q + 0][oo] + s1 * toep_val(Wseed, k0 + kq + 2 * q + 0, o0 + oo);
            float v1 = s0 * T[kq + 2 * q + 1][oo] + s1 * toep_val(Wseed, k0 + kq + 2 * q + 1, o0 + oo);
            r[q] = (unsigned)f2bf(v0) | ((unsigned)f2bf(v1) << 16);
        }
        *(uint4*)&Wt[(size_t)(o0 + oo) * 1024 + k0 + kq] = make_uint4(r[0], r[1], r[2], r[3]);
    }
}

// ---------------- main GEMM: 128x128, BK=32, 512 threads (8 waves, 4Mx2N) --------
// grid 512 = 2 blocks/CU -> 16 waves/CU (2x R11's TLP).
// A: fp32 x staged via async16, XOR-swizzled (16B chunk ^ row&7), cvt after read.
// B: bf16 Wt staged via async16, NOW XOR-swizzled too (16B chunk ^ row&3) — fixes
//    the 8-way bank conflict present since R1 (3.1M conflicts/dispatch).
// One vmcnt(0)+lgkmcnt(0)+barrier per K-step (2-phase dbuf, R4/R11-verified).
#define BM 128
#define BN 128
#define BK 32
#define NKT 32   // 1024 / 32

__global__ __launch_bounds__(512, 2) void gemm_kernel(const float* __restrict__ Xf,
                                                      const ushort_t* __restrict__ Wt,
                                                      const float* __restrict__ bseed,
                                                      const float* __restrict__ bsig,
                                                      const float* __restrict__ asig,
                                                      float* __restrict__ out) {
    // dbuf x (A 16KB fp32 + B 8KB bf16) = 48 KB
    __shared__ ushort_t lds[24576];
    ushort_t* At0 = lds;            // 8192 ushorts = 16KB (128 rows x 32 fp32)
    ushort_t* Bt0 = lds + 8192;     // 4096 ushorts = 8KB  (128 rows x 32 bf16)
    ushort_t* At1 = lds + 12288;
    ushort_t* Bt1 = lds + 20480;

    const int t = threadIdx.x;        // 0..511
    const int wv = t >> 6;            // 0..7
    const int lane = t & 63;

    // XCD-aware swizzle (512 blocks, bijective)
    const int orig = blockIdx.x;
    const int g = orig & 7;
    const int within = orig >> 3;           // 0..63
    const int rb = g * 8 + (within >> 3);   // row-block 0..63
    const int cb = within & 7;              // col-block 0..7
    const int brow = rb * BM;
    const int bcol = cb * BN;

    // ---- A staging map: 8 threads per 128B row (rows 0..63 per call) ----
    const int ra = t >> 3;                        // 0..63
    const int ca = (t & 7) ^ (ra & 7);            // inverse-swizzled 16B chunk
    const float* gAsw = Xf + (size_t)(brow + ra) * 1024 + 4 * ca;

    // ---- B staging map: 4 threads per 64B row (all 128 rows in one call) ----
    const int rbb = t >> 2;                       // 0..127
    const int cbk = (t & 3) ^ (rbb & 3);          // inverse-swizzled 16B chunk
    const ushort_t* gBsw = Wt + (size_t)(bcol + rbb) * 1024 + 8 * cbk;

    f32x4 acc[2][4];
    #pragma unroll
    for (int i = 0; i < 2; ++i)
        #pragma unroll
        for (int j = 0; j < 4; ++j) acc[i][j] = (f32x4){0.f, 0.f, 0.f, 0.f};

    // wave decomposition: 4 M-groups x 2 N-groups; wave = 32 rows x 64 cols
    const int wr = (wv >> 1) * 32;     // 0,32,64,96
    const int wcn = (wv & 1) * 64;     // 0,64
    const int fr = lane & 15;
    const int kg = (lane >> 4) * 8;    // k-offset (elements)
    const int c0 = (lane >> 4) * 2;    // A 16B-chunk base (2 chunks per kg)

    // epilogue scalars precomputed + pinned
    float bs0, bs1, as0, as1;
    softmax2(bsig, bs0, bs1);
    softmax2(asig, as0, as1);
    float bias[4];
    #pragma unroll
    for (int ni = 0; ni < 4; ++ni)
        bias[ni] = bs0 * bseed[bcol + wcn + ni * 16 + fr];
    asm volatile("" :: "v"(bias[0]), "v"(bias[1]), "v"(bias[2]), "v"(bias[3]),
                       "v"(as0), "v"(as1));
    asm volatile("" ::: "memory");

// A: 2 calls x 8KB (512 threads x 16B); dest linear (byte = t*16 = row*128 + chunk*16)
#define STAGEA(Abuf, ko)                                           \
    do {                                                           \
        async16((Abuf) + wv * 512,        gAsw + (ko));            \
        async16((Abuf) + 4096 + wv * 512, gAsw + 65536 + (ko));    \
    } while (0)

// B: 1 call x 8KB; dest linear (byte = t*16 = row*64 + chunk*16)
#define STAGEB(Bbuf, ko)                                   \
    do {                                                   \
        async16((Bbuf) + wv * 512, gBsw + (ko));           \
    } while (0)

#define COMPUTE(Abuf, Bbuf)                                                        \
    do {                                                                           \
        const float* Af_ = (const float*)(Abuf);                                   \
        bf16x8 af[2], bf[4];                                                       \
        _Pragma("unroll")                                                          \
        for (int mi = 0; mi < 2; ++mi) {                                           \
            int row_ = wr + mi * 16 + fr;                                          \
            f32x4 lo_ = *(const f32x4*)&Af_[row_ * 32 + (((c0)     ^ (row_ & 7)) << 2)]; \
            f32x4 hi_ = *(const f32x4*)&Af_[row_ * 32 + (((c0 + 1) ^ (row_ & 7)) << 2)]; \
            bf16x8 a_;                                                             \
            _Pragma("unroll")                                                      \
            for (int j_ = 0; j_ < 4; ++j_) {                                       \
                a_[j_]     = (__bf16)lo_[j_];                                      \
                a_[4 + j_] = (__bf16)hi_[j_];                                      \
            }                                                                      \
            af[mi] = a_;                                                           \
        }                                                                          \
        _Pragma("unroll")                                                          \
        for (int ni = 0; ni < 4; ++ni) {                                           \
            int rb_ = wcn + ni * 16 + fr;                                          \
            int ch_ = ((kg >> 3) ^ (rb_ & 3)) << 3;                                \
            bf[ni] = *(const bf16x8*)&(Bbuf)[rb_ * 32 + ch_];                      \
        }                                                                          \
        _Pragma("unroll")                                                          \
        for (int mi = 0; mi < 2; ++mi)                                             \
            _Pragma("unroll")                                                      \
            for (int ni = 0; ni < 4; ++ni)                                         \
                acc[mi][ni] = __builtin_amdgcn_mfma_f32_16x16x32_bf16(             \
                    af[mi], bf[ni], acc[mi][ni], 0, 0, 0);                         \
    } while (0)

#define SYNC() do { asm volatile("s_waitcnt vmcnt(0) lgkmcnt(0)" ::: "memory");    \
                    __builtin_amdgcn_s_barrier(); } while (0)

    // prologue: K-step 0 into buf0
    STAGEA(At0, 0);
    STAGEB(Bt0, 0);
    SYNC();
    // main: 15 double-iterations
    for (int it = 0; it < 15; ++it) {
        STAGEA(At1, (2 * it + 1) * BK);       // next tile in flight across compute
        STAGEB(Bt1, (2 * it + 1) * BK);
        COMPUTE(At0, Bt0);
        SYNC();
        STAGEA(At0, (2 * it + 2) * BK);
        STAGEB(Bt0, (2 * it + 2) * BK);
        COMPUTE(At1, Bt1);
        SYNC();
    }
    // tail: K-steps 30, 31
    STAGEA(At1, 31 * BK);
    STAGEB(Bt1, 31 * BK);
    COMPUTE(At0, Bt0);
    SYNC();
    COMPUTE(At1, Bt1);

    // epilogue: bias + activation mixture
    #pragma unroll
    for (int ni = 0; ni < 4; ++ni) {
        int col = bcol + wcn + ni * 16 + fr;
        #pragma unroll
        for (int mi = 0; mi < 2; ++mi) {
            int row = brow + wr + mi * 16 + (lane >> 4) * 4;
            #pragma unroll
            for (int r = 0; r < 4; ++r) {
                float v = acc[mi][ni][r] + bias[ni];
                out[(size_t)(row + r) * 1024 + col] = as0 * v + as1 * fmaxf(v, 0.f);
            }
        }
    }
#undef STAGEA
#undef STAGEB
#undef COMPUTE
#undef SYNC
}

// ---------------- fallback (only if workspace too small): naive fp32 ----------------
__global__ __launch_bounds__(256) void naive_kernel(const float* __restrict__ x,
                                                    const float* __restrict__ Wseed,
                                                    const float* __restrict__ bseed,
                                                    const float* __restrict__ Wsig,
                                                    const float* __restrict__ bsig,
                                                    const float* __restrict__ asig,
                                                    float* __restrict__ out) {
    int idx = blockIdx.x * 256 + threadIdx.x;
    int b = idx >> 10, o = idx & 1023;
    float ws0, ws1, bs0, bs1, as0, as1;
    softmax2(Wsig, ws0, ws1);
    softmax2(bsig, bs0, bs1);
    softmax2(asig, as0, as1);
    float s = 0.f;
    const float* xr = x + (size_t)b * 1024;
    for (int k = 0; k < 1024; ++k) {
        float wc = ws0 * Wseed[((size_t)k << 10) + o] + ws1 * toep_val(Wseed, k, o);
        s += xr[k] * wc;
    }
    float v = s + bs0 * bseed[o];
    out[idx] = as0 * v + as1 * fmaxf(v, 0.f);
}

extern "C" void kernel_launch(void* const* d_in, const int* in_sizes, int n_in,
                              void* d_out, int out_size, void* d_ws, size_t ws_size,
                              hipStream_t stream) {
    const float* x     = (const float*)d_in[0];
    const float* Wseed = (const float*)d_in[1];
    const float* bseed = (const float*)d_in[2];
    const float* Wsig  = (const float*)d_in[3];
    const float* bsig  = (const float*)d_in[4];
    const float* Asig  = (const float*)d_in[5];
    float* out = (float*)d_out;

    const size_t need = (2u << 20) + 1024;
    if (ws_size < need) {
        naive_kernel<<<dim3(8192 * 1024 / 256), dim3(256), 0, stream>>>(
            x, Wseed, bseed, Wsig, bsig, Asig, out);
        return;
    }

    ushort_t* Wt = (ushort_t*)d_ws;   // 2 MB: W_core^T bf16 [1024][1024]

    prep_w_kernel<<<dim3(256), dim3(256), 0, stream>>>(Wseed, Wsig, Wt);
    gemm_kernel<<<dim3(512), dim3(512), 0, stream>>>(x, Wt, bseed, bsig, Asig, out);
}